// Round 11
// baseline (339.201 us; speedup 1.0000x reference)
//
#include <hip/hip_runtime.h>
#include <hip/hip_bf16.h>
#include <cstdint>
#include <cstddef>

// Problem dims (fixed by the reference)
#define T_STEPS 2048
#define BATCH   8
#define D_DIM   1024
#define M_ROWS  (T_STEPS * BATCH)   // 16384 rows of x
#define N_COLS  (2 * D_DIM)         // 2048: W_alpha rows ++ W_x rows
#define K_DIM   D_DIM               // 1024
#define NCH     (BATCH * D_DIM)     // 8192 independent recurrence channels

// GEMM tiling: 128x128 tile, BK=64, double-buffered LDS (one barrier/K-step)
#define BM 128
#define BN 128
#define BK 64
#define NKT (K_DIM / BK)   // 16 K-steps

typedef __bf16 bf16x8 __attribute__((ext_vector_type(8)));
typedef float  f32x4  __attribute__((ext_vector_type(4)));

#define C2L_CONST 2.88539008177792681472f   // 2*log2(e)

__device__ __forceinline__ unsigned short f2bf_rne(float f) {
    union { float f; unsigned u; } c; c.f = f;
    unsigned u = c.u;
    u += 0x7fffu + ((u >> 16) & 1u);   // round-to-nearest-even (inputs finite)
    return (unsigned short)(u >> 16);
}

__device__ __forceinline__ float sigmoid_f(float z) {
    return 1.0f / (1.0f + __expf(-z));
}

// async global -> LDS DMA, 16 B per lane; LDS dest = wave-uniform base + lane*16
__device__ __forceinline__ void glds16(const void* gptr, void* lptr) {
    __builtin_amdgcn_global_load_lds(
        (const __attribute__((address_space(1))) unsigned int*)gptr,
        (__attribute__((address_space(3))) unsigned int*)lptr,
        16, 0, 0);
}

// ---------------------------------------------------------------------------
// fp32 -> bf16 convert (vectorized x4)
// ---------------------------------------------------------------------------
__global__ void cvt_bf16_kernel(const float* __restrict__ src,
                                unsigned short* __restrict__ dst, int n4) {
    int i = blockIdx.x * blockDim.x + threadIdx.x;
    if (i >= n4) return;
    float4 v = reinterpret_cast<const float4*>(src)[i];
    ushort4 o;
    o.x = f2bf_rne(v.x); o.y = f2bf_rne(v.y);
    o.z = f2bf_rne(v.z); o.w = f2bf_rne(v.w);
    reinterpret_cast<ushort4*>(dst)[i] = o;
}

// ---------------------------------------------------------------------------
// Fused bf16 MFMA GEMM, BK=64 + block-XOR LDS swizzle + LDS DOUBLE-BUFFER.
//   out[m,n] = sum_k x[m,k] * Wc[n,k]
//   n <  1024 -> alpha_out = sigmoid(acc + b_alpha[n])
//   n >= 1024 -> wx_out    = C2L * (acc + b[n-1024])   [pre-scaled for scan]
// Per K-step: issue next-tile glds16 FIRST, then ds_read+MFMA current buffer,
// then ONE __syncthreads. Stage's HBM latency hides under the MFMA block;
// barrier count halves. Single-barrier correctness: iter k stages buf^1 /
// reads buf; the barrier (with its vmcnt drain) ends iter k with reads-of-buf
// done and stage-of-buf^1 resident; iter k+1 flips. No WAR window.
// ---------------------------------------------------------------------------
__global__ __launch_bounds__(256, 2)
void gemm_kernel(const unsigned short* __restrict__ A,   // [M][K] bf16 (x)
                 const unsigned short* __restrict__ Bm,  // [N][K] bf16 (W_alpha ++ W_x)
                 const float* __restrict__ b_alpha,      // [D]
                 const float* __restrict__ b_x,          // [D]
                 float* __restrict__ alpha_out,          // [M][D] fp32
                 float* __restrict__ wx_out)             // [M][D] fp32 (C2L-scaled)
{
    __shared__ unsigned short sA[2][BM * BK];   // 2 x 16 KB
    __shared__ unsigned short sB[2][BN * BK];   // 2 x 16 KB

    const int tid  = threadIdx.x;
    const int wave = tid >> 6;
    const int lane = tid & 63;

    // XCD swizzle: grid is (16, 128) = 2048 wgs; 2048 % 8 == 0 -> bijective
    const int orig = blockIdx.y * 16 + blockIdx.x;
    const int swz  = (orig & 7) * 256 + (orig >> 3);
    const int rowBase = (swz >> 4) * BM;
    const int colBase = (swz & 15) * BN;

    const int wr = (wave >> 1) * 64;
    const int wc = (wave & 1) * 64;

    const int laneHi = lane >> 4;           // 0..3
    const int laneLo = lane & 15;
    const int rxor   = laneLo & 7;          // row&7 for fragment reads

    // DMA staging: 8 rows per glds16; source col block XOR-swizzled
    const int dRow   = lane >> 3;                    // 0..7
    const int dColSw = ((lane & 7) ^ dRow) * 8;      // shorts

    auto stage = [&](int bufIdx, int k0) {
#pragma unroll
        for (int p = 0; p < 4; ++p) {
            const int seg = wave * 4 + p;   // 8-row segment index, 0..15
            glds16(A + (size_t)(rowBase + seg * 8 + dRow) * K_DIM + k0 + dColSw,
                   &sA[bufIdx][seg * 512]);
            glds16(Bm + (size_t)(colBase + seg * 8 + dRow) * K_DIM + k0 + dColSw,
                   &sB[bufIdx][seg * 512]);
        }
    };

    f32x4 acc[4][4];
#pragma unroll
    for (int i = 0; i < 4; i++)
#pragma unroll
        for (int j = 0; j < 4; j++)
            acc[i][j] = (f32x4)(0.0f);

    stage(0, 0);
    __syncthreads();   // prologue drain: buf0 resident

    int buf = 0;
    for (int kt = 0; kt < NKT; ++kt) {
        if (kt + 1 < NKT) stage(buf ^ 1, (kt + 1) * BK);   // overlap w/ MFMA

#pragma unroll
        for (int kk = 0; kk < 2; ++kk) {
            bf16x8 af[4], bfr[4];
#pragma unroll
            for (int i = 0; i < 4; i++) {
                const int row = wr + i * 16 + laneLo;
                af[i] = *reinterpret_cast<const bf16x8*>(
                    &sA[buf][row * BK + (((kk << 2) + laneHi) ^ rxor) * 8]);
            }
#pragma unroll
            for (int j = 0; j < 4; j++) {
                const int row = wc + j * 16 + laneLo;
                bfr[j] = *reinterpret_cast<const bf16x8*>(
                    &sB[buf][row * BK + (((kk << 2) + laneHi) ^ rxor) * 8]);
            }
#pragma unroll
            for (int i = 0; i < 4; i++)
#pragma unroll
                for (int j = 0; j < 4; j++)
                    acc[i][j] = __builtin_amdgcn_mfma_f32_16x16x32_bf16(
                        af[i], bfr[j], acc[i][j], 0, 0, 0);
        }
        __syncthreads();   // ONE barrier/K-step: reads done + next stage drained
        buf ^= 1;
    }

    // Epilogue. C/D layout: col = lane&15, row = (lane>>4)*4 + reg  [m89/m91]
#pragma unroll
    for (int i = 0; i < 4; i++) {
        int row = rowBase + wr + i * 16 + laneHi * 4;
#pragma unroll
        for (int j = 0; j < 4; j++) {
            int col = colBase + wc + j * 16 + laneLo;
            if (col < D_DIM) {
                float bias = b_alpha[col];
#pragma unroll
                for (int r = 0; r < 4; r++) {
                    float z = acc[i][j][r] + bias;
                    alpha_out[(size_t)(row + r) * D_DIM + col] = sigmoid_f(z);
                }
            } else {
                int c2 = col - D_DIM;
                float bias = b_x[c2];
#pragma unroll
                for (int r = 0; r < 4; r++)
                    wx_out[(size_t)(row + r) * D_DIM + c2] =
                        (acc[i][j][r] + bias) * C2L_CONST;   // pre-scaled
            }
        }
    }
}

// ---------------------------------------------------------------------------
// Sequential scan v9: 3-wave role split + register-preloaded tile (v8,
// validated) + ISSUE-TRIMMED chain.
//   R9 diagnosis: scan is issue-bound on the compute wave (~100 cy/step vs
//   ~44 cy chain latency). Trims: (a) wx PRE-SCALED by C2L in GEMM epilogue;
//   (b) h-route z-update zl = fma(h, C2L, cw') kills 2 shadow VALU for +1
//   chain fma (issue-bound -> net win); (c) negation folded into fma mod.
//   Per step: exp2, e+1, rcp, u=1-a, t2u=u+u, m=fma(a,h,u),
//             h=fma(-t2u,r,m), zl=fma(h,C2L,cw')  = 2 trans + 6 VALU + 1 write.
//   Loader/storer/barriers/counted-vmcnt: identical to v7/v8 (validated).
// ---------------------------------------------------------------------------
#define TT   32
#define NT   (T_STEPS / TT)   // 64 tiles
#define PF   6                // prefetch distance (tiles)
#define CPB  32               // channels per block
#define SHS  36               // sH row stride (floats), padded

__global__ __launch_bounds__(192)
void scan_kernel(const float* __restrict__ alpha,  // [T][NCH]
                 const float* __restrict__ cwx,    // [T][NCH]  (= C2L*(Wx+b))
                 const float* __restrict__ h0,     // [NCH]
                 float* __restrict__ out,          // [T][NCH]
                 float* __restrict__ hout)         // [T+1][NCH]
{
    __shared__ float sIn[8][2][TT * CPB];   // [buf][0=alpha,1=cwx]  64 KB
    __shared__ float sH[2][TT * SHS];       // h ring, padded        9 KB

    const int lane = threadIdx.x & 63;
    const int wid  = threadIdx.x >> 6;
    const int ch0  = blockIdx.x * CPB;

    const float C2L = C2L_CONST;

    // loader/storer lane mapping (16 B per lane): 8 lanes per timestep
    const int q8 = lane >> 3;            // timestep sub-offset 0..7
    const int c4 = (lane & 7) * 4;       // channel group

    float h = 0.0f;

    // ---- prologue ----
    if (wid == 1) {
        // stage tiles 0..PF-1 (6 bursts x 8 ops = 48 outstanding)
#pragma unroll
        for (int t = 0; t < PF; ++t)
#pragma unroll
            for (int p = 0; p < TT / 8; ++p) {
                const size_t g = (size_t)(t * TT + p * 8 + q8) * NCH + ch0 + c4;
                glds16(alpha + g, &sIn[t][0][p * 256]);
                glds16(cwx   + g, &sIn[t][1][p * 256]);
            }
        // complete G_0; keep G_1..G_5 (40 ops) in flight
        asm volatile("s_waitcnt vmcnt(40)" ::: "memory");
    } else if (wid == 0) {
        if (lane < CPB) h = h0[ch0 + lane];
    } else {
        if (lane < CPB) hout[ch0 + lane] = h0[ch0 + lane];   // row 0
    }
    __builtin_amdgcn_s_barrier();
    __builtin_amdgcn_sched_barrier(0);

    // ---- main loop: one barrier per tile ----
    for (int tile = 0; tile < NT; ++tile) {
        if (wid == 0) {
            // COMPUTE tile from sIn[tile&7]; h trace -> sH[tile&1]
            const float* sA  = &sIn[tile & 7][0][0];
            const float* sW  = &sIn[tile & 7][1][0];
            float* sHc       = &sH[tile & 1][0];
            if (lane < CPB) {
                // (1) independent register burst (64 ds_read_b32)
                float aR[TT], wR[TT];   // wR = C2L*w (pre-scaled)
#pragma unroll
                for (int ts = 0; ts < TT; ++ts) {
                    aR[ts] = sA[ts * CPB + lane];
                    wR[ts] = sW[ts * CPB + lane];
                }
                __builtin_amdgcn_sched_barrier(0);   // pin burst above chain
                // (2) pure-VALU serial chain
                float zl = fmaf(h, C2L, wR[0]);
#pragma unroll
                for (int ts = 0; ts < TT; ++ts) {
                    const float a   = aR[ts];
                    const float e   = __builtin_amdgcn_exp2f(zl);      // CHAIN
                    const float u   = 1.0f - a;                        // shadow
                    const float t2u = u + u;                           // shadow
                    const float m   = fmaf(a, h, u);                   // shadow
                    const float r   = __builtin_amdgcn_rcpf(e + 1.0f); // CHAIN
                    h = fmaf(-t2u, r, m);                              // CHAIN
                    if (ts < TT - 1) zl = fmaf(h, C2L, wR[ts + 1]);    // CHAIN
                    sHc[ts * SHS + lane] = h;
                }
            }
            asm volatile("s_waitcnt lgkmcnt(0)" ::: "memory");
            __builtin_amdgcn_sched_barrier(0);
        } else if (wid == 1) {
            // LOADER: stage tile+PF, then guarantee tile+1 is resident
            if (tile + PF < NT) {
                const int b  = (tile + PF) & 7;
                const int t0 = (tile + PF) * TT;
#pragma unroll
                for (int p = 0; p < TT / 8; ++p) {
                    const size_t g = (size_t)(t0 + p * 8 + q8) * NCH + ch0 + c4;
                    glds16(alpha + g, &sIn[b][0][p * 256]);
                    glds16(cwx   + g, &sIn[b][1][p * 256]);
                }
            }
            // counted drain: complete the burst for tile+1, keep the rest
            {
                const int rem = NT - 1 - tile;
                if (rem >= PF) {
                    asm volatile("s_waitcnt vmcnt(40)" ::: "memory");
                } else if (rem == 5) {
                    asm volatile("s_waitcnt vmcnt(32)" ::: "memory");
                } else if (rem == 4) {
                    asm volatile("s_waitcnt vmcnt(24)" ::: "memory");
                } else if (rem == 3) {
                    asm volatile("s_waitcnt vmcnt(16)" ::: "memory");
                } else if (rem == 2) {
                    asm volatile("s_waitcnt vmcnt(8)" ::: "memory");
                } else if (rem == 1) {
                    asm volatile("s_waitcnt vmcnt(0)" ::: "memory");
                }   // rem == 0: nothing outstanding
            }
            __builtin_amdgcn_sched_barrier(0);
        } else {
            // STORER: flush tile-1's h trace; fused out = h^2 * sigmoid(h)
            if (tile >= 1) {
                const float* sHs = &sH[(tile - 1) & 1][0];
                const int tb = (tile - 1) * TT;
#pragma unroll
                for (int i = 0; i < TT / 8; ++i) {
                    const int tsrow = i * 8 + q8;
                    const float4 hv = *reinterpret_cast<const float4*>(
                        &sHs[tsrow * SHS + c4]);
                    *reinterpret_cast<float4*>(
                        &hout[(size_t)(tb + tsrow + 1) * NCH + ch0 + c4]) = hv;
                    float4 o;
                    o.x = hv.x * hv.x * sigmoid_f(hv.x);
                    o.y = hv.y * hv.y * sigmoid_f(hv.y);
                    o.z = hv.z * hv.z * sigmoid_f(hv.z);
                    o.w = hv.w * hv.w * sigmoid_f(hv.w);
                    *reinterpret_cast<float4*>(
                        &out[(size_t)(tb + tsrow) * NCH + ch0 + c4]) = o;
                }
            }
        }
        __builtin_amdgcn_s_barrier();
        __builtin_amdgcn_sched_barrier(0);
    }

    // ---- epilogue: flush final tile ----
    if (wid == 2) {
        const float* sHs = &sH[(NT - 1) & 1][0];
        const int tb = (NT - 1) * TT;
#pragma unroll
        for (int i = 0; i < TT / 8; ++i) {
            const int tsrow = i * 8 + q8;
            const float4 hv = *reinterpret_cast<const float4*>(
                &sHs[tsrow * SHS + c4]);
            *reinterpret_cast<float4*>(
                &hout[(size_t)(tb + tsrow + 1) * NCH + ch0 + c4]) = hv;
            float4 o;
            o.x = hv.x * hv.x * sigmoid_f(hv.x);
            o.y = hv.y * hv.y * sigmoid_f(hv.y);
            o.z = hv.z * hv.z * sigmoid_f(hv.z);
            o.w = hv.w * hv.w * sigmoid_f(hv.w);
            *reinterpret_cast<float4*>(
                &out[(size_t)(tb + tsrow) * NCH + ch0 + c4]) = o;
        }
    }
}

// ---------------------------------------------------------------------------
extern "C" void kernel_launch(void* const* d_in, const int* in_sizes, int n_in,
                              void* d_out, int out_size, void* d_ws, size_t ws_size,
                              hipStream_t stream) {
    const float* x       = (const float*)d_in[0];  // [T,B,D]
    const float* h0      = (const float*)d_in[1];  // [B,D]
    const float* W_alpha = (const float*)d_in[2];  // [D,D]
    const float* b_alpha = (const float*)d_in[3];  // [D]
    const float* W_x     = (const float*)d_in[4];  // [D,D]
    const float* b       = (const float*)d_in[5];  // [D]

    float* out  = (float*)d_out;                              // [T,B,D]
    float* hout = out + (size_t)T_STEPS * BATCH * D_DIM;      // [T+1,B,D]

    // Workspace layout (~164 MB):
    //   alpha fp32 (64 MB) | cwx fp32 (64 MB) | x bf16 (32 MB) | Wc bf16 (4 MB)
    float* ws_alpha = (float*)d_ws;
    float* ws_wx    = ws_alpha + (size_t)M_ROWS * D_DIM;
    unsigned short* ws_x = (unsigned short*)(ws_wx + (size_t)M_ROWS * D_DIM);
    unsigned short* ws_W = ws_x + (size_t)M_ROWS * K_DIM;

    // 1) convert x, W_alpha, W_x to bf16
    {
        int n4 = M_ROWS * K_DIM / 4;
        cvt_bf16_kernel<<<(n4 + 255) / 256, 256, 0, stream>>>(x, ws_x, n4);
    }
    {
        int n4 = D_DIM * K_DIM / 4;
        cvt_bf16_kernel<<<(n4 + 255) / 256, 256, 0, stream>>>(W_alpha, ws_W, n4);
        cvt_bf16_kernel<<<(n4 + 255) / 256, 256, 0, stream>>>(
            W_x, ws_W + (size_t)D_DIM * K_DIM, n4);
    }

    // 2) fused GEMM (dbuf, one barrier/K-step) + bias/sigmoid/C2L epilogue
    {
        dim3 grid(N_COLS / BN, M_ROWS / BM);   // (16, 128)
        gemm_kernel<<<grid, 256, 0, stream>>>(ws_x, ws_W, b_alpha, b,
                                              ws_alpha, ws_wx);
    }

    // 3) sequential scan: 256 blocks x 3 waves (loader / compute / storer)
    scan_kernel<<<NCH / CPB, 192, 0, stream>>>(ws_alpha, ws_wx, h0, out, hout);
}

// Round 12
// 337.109 us; speedup vs baseline: 1.0062x; 1.0062x over previous
//
#include <hip/hip_runtime.h>
#include <hip/hip_bf16.h>
#include <cstdint>
#include <cstddef>

// Problem dims (fixed by the reference)
#define T_STEPS 2048
#define BATCH   8
#define D_DIM   1024
#define M_ROWS  (T_STEPS * BATCH)   // 16384 rows of x
#define N_COLS  (2 * D_DIM)         // 2048: W_alpha rows ++ W_x rows
#define K_DIM   D_DIM               // 1024
#define NCH     (BATCH * D_DIM)     // 8192 independent recurrence channels

// GEMM tiling: 128x128 tile, BK=64, SINGLE-buffer LDS (R9-validated; R11's
// dbuf = 64KB LDS cut occupancy 3->2 blocks/CU and cost +20us -- m132 lesson)
#define BM 128
#define BN 128
#define BK 64

typedef __bf16 bf16x8 __attribute__((ext_vector_type(8)));
typedef float  f32x4  __attribute__((ext_vector_type(4)));

#define C2L_CONST 2.88539008177792681472f   // 2*log2(e)

__device__ __forceinline__ unsigned short f2bf_rne(float f) {
    union { float f; unsigned u; } c; c.f = f;
    unsigned u = c.u;
    u += 0x7fffu + ((u >> 16) & 1u);   // round-to-nearest-even (inputs finite)
    return (unsigned short)(u >> 16);
}

__device__ __forceinline__ float sigmoid_f(float z) {
    return 1.0f / (1.0f + __expf(-z));
}

// async global -> LDS DMA, 16 B per lane; LDS dest = wave-uniform base + lane*16
__device__ __forceinline__ void glds16(const void* gptr, void* lptr) {
    __builtin_amdgcn_global_load_lds(
        (const __attribute__((address_space(1))) unsigned int*)gptr,
        (__attribute__((address_space(3))) unsigned int*)lptr,
        16, 0, 0);
}

// ---------------------------------------------------------------------------
// fp32 -> bf16 convert (vectorized x4)
// ---------------------------------------------------------------------------
__global__ void cvt_bf16_kernel(const float* __restrict__ src,
                                unsigned short* __restrict__ dst, int n4) {
    int i = blockIdx.x * blockDim.x + threadIdx.x;
    if (i >= n4) return;
    float4 v = reinterpret_cast<const float4*>(src)[i];
    ushort4 o;
    o.x = f2bf_rne(v.x); o.y = f2bf_rne(v.y);
    o.z = f2bf_rne(v.z); o.w = f2bf_rne(v.w);
    reinterpret_cast<ushort4*>(dst)[i] = o;
}

// ---------------------------------------------------------------------------
// Fused bf16 MFMA GEMM, BK=64 + block-XOR LDS swizzle, single-buffer
// (exact R9-validated structure; occupancy 3 blocks/CU hides staging via
// inter-block wave overlap -- m114 mechanism).
//   out[m,n] = sum_k x[m,k] * Wc[n,k]
//   n <  1024 -> alpha_out = sigmoid(acc + b_alpha[n])
//   n >= 1024 -> wx_out    = C2L * (acc + b[n-1024])   [pre-scaled for scan]
// ---------------------------------------------------------------------------
__global__ __launch_bounds__(256, 2)
void gemm_kernel(const unsigned short* __restrict__ A,   // [M][K] bf16 (x)
                 const unsigned short* __restrict__ Bm,  // [N][K] bf16 (W_alpha ++ W_x)
                 const float* __restrict__ b_alpha,      // [D]
                 const float* __restrict__ b_x,          // [D]
                 float* __restrict__ alpha_out,          // [M][D] fp32
                 float* __restrict__ wx_out)             // [M][D] fp32 (C2L-scaled)
{
    __shared__ unsigned short sA[BM * BK];   // 16 KB
    __shared__ unsigned short sB[BN * BK];   // 16 KB

    const int tid  = threadIdx.x;
    const int wave = tid >> 6;
    const int lane = tid & 63;

    // XCD swizzle: grid is (16, 128) = 2048 wgs; 2048 % 8 == 0 -> bijective
    const int orig = blockIdx.y * 16 + blockIdx.x;
    const int swz  = (orig & 7) * 256 + (orig >> 3);
    const int rowBase = (swz >> 4) * BM;
    const int colBase = (swz & 15) * BN;

    const int wr = (wave >> 1) * 64;
    const int wc = (wave & 1) * 64;

    const int laneHi = lane >> 4;           // 0..3
    const int laneLo = lane & 15;
    const int rxor   = laneLo & 7;          // row&7 for fragment reads

    // DMA staging: 8 rows per glds16; source col block XOR-swizzled
    const int dRow   = lane >> 3;                    // 0..7
    const int dColSw = ((lane & 7) ^ dRow) * 8;      // shorts

    f32x4 acc[4][4];
#pragma unroll
    for (int i = 0; i < 4; i++)
#pragma unroll
        for (int j = 0; j < 4; j++)
            acc[i][j] = (f32x4)(0.0f);

    for (int k0 = 0; k0 < K_DIM; k0 += BK) {
#pragma unroll
        for (int p = 0; p < 4; ++p) {
            const int seg = wave * 4 + p;   // 8-row segment index, 0..15
            glds16(A + (size_t)(rowBase + seg * 8 + dRow) * K_DIM + k0 + dColSw,
                   &sA[seg * 512]);
            glds16(Bm + (size_t)(colBase + seg * 8 + dRow) * K_DIM + k0 + dColSw,
                   &sB[seg * 512]);
        }
        __syncthreads();   // drains vmcnt(0) -> LDS tiles ready

#pragma unroll
        for (int kk = 0; kk < 2; ++kk) {
            bf16x8 af[4], bfr[4];
#pragma unroll
            for (int i = 0; i < 4; i++) {
                const int row = wr + i * 16 + laneLo;
                af[i] = *reinterpret_cast<const bf16x8*>(
                    &sA[row * BK + (((kk << 2) + laneHi) ^ rxor) * 8]);
            }
#pragma unroll
            for (int j = 0; j < 4; j++) {
                const int row = wc + j * 16 + laneLo;
                bfr[j] = *reinterpret_cast<const bf16x8*>(
                    &sB[row * BK + (((kk << 2) + laneHi) ^ rxor) * 8]);
            }
#pragma unroll
            for (int i = 0; i < 4; i++)
#pragma unroll
                for (int j = 0; j < 4; j++)
                    acc[i][j] = __builtin_amdgcn_mfma_f32_16x16x32_bf16(
                        af[i], bfr[j], acc[i][j], 0, 0, 0);
        }
        __syncthreads();   // all reads done; LDS free for next k-step
    }

    // Epilogue. C/D layout: col = lane&15, row = (lane>>4)*4 + reg  [m89/m91]
#pragma unroll
    for (int i = 0; i < 4; i++) {
        int row = rowBase + wr + i * 16 + laneHi * 4;
#pragma unroll
        for (int j = 0; j < 4; j++) {
            int col = colBase + wc + j * 16 + laneLo;
            if (col < D_DIM) {
                float bias = b_alpha[col];
#pragma unroll
                for (int r = 0; r < 4; r++) {
                    float z = acc[i][j][r] + bias;
                    alpha_out[(size_t)(row + r) * D_DIM + col] = sigmoid_f(z);
                }
            } else {
                int c2 = col - D_DIM;
                float bias = b_x[c2];
#pragma unroll
                for (int r = 0; r < 4; r++)
                    wx_out[(size_t)(row + r) * D_DIM + c2] =
                        (acc[i][j][r] + bias) * C2L_CONST;   // pre-scaled
            }
        }
    }
}

// ---------------------------------------------------------------------------
// Sequential scan v10: 3-wave role split + register burst (R9) + issue trim
// (R11) + K-ROUTE 4-deep chain.
//   R11 status: scan ~66us = ~77 cy/step with issue ~24 cy -> chain-latency
//   bound again. v9 chain was 5 deep (exp2->add->rcp->fma(h)->fma(zl)).
//   K-route: zl' = fma(-C2L*t2u, r, K), K = fma(m, C2L, w') and C2L*t2u
//   computed in the trans shadow -> chain = exp2->add->rcp->fma (4 deep);
//   h = fma(-t2u, r, m) runs off-chain in parallel. (v7's algebra, which
//   passed refcheck, now paired with the register burst that makes the
//   chain the binding constraint.)
//   Loader/storer/barriers/counted-vmcnt: identical to v7/v8/v9 (validated).
// ---------------------------------------------------------------------------
#define TT   32
#define NT   (T_STEPS / TT)   // 64 tiles
#define PF   6                // prefetch distance (tiles)
#define CPB  32               // channels per block
#define SHS  36               // sH row stride (floats), padded

__global__ __launch_bounds__(192)
void scan_kernel(const float* __restrict__ alpha,  // [T][NCH]
                 const float* __restrict__ cwx,    // [T][NCH]  (= C2L*(Wx+b))
                 const float* __restrict__ h0,     // [NCH]
                 float* __restrict__ out,          // [T][NCH]
                 float* __restrict__ hout)         // [T+1][NCH]
{
    __shared__ float sIn[8][2][TT * CPB];   // [buf][0=alpha,1=cwx]  64 KB
    __shared__ float sH[2][TT * SHS];       // h ring, padded        9 KB

    const int lane = threadIdx.x & 63;
    const int wid  = threadIdx.x >> 6;
    const int ch0  = blockIdx.x * CPB;

    const float C2L = C2L_CONST;

    // loader/storer lane mapping (16 B per lane): 8 lanes per timestep
    const int q8 = lane >> 3;            // timestep sub-offset 0..7
    const int c4 = (lane & 7) * 4;       // channel group

    float h = 0.0f;

    // ---- prologue ----
    if (wid == 1) {
        // stage tiles 0..PF-1 (6 bursts x 8 ops = 48 outstanding)
#pragma unroll
        for (int t = 0; t < PF; ++t)
#pragma unroll
            for (int p = 0; p < TT / 8; ++p) {
                const size_t g = (size_t)(t * TT + p * 8 + q8) * NCH + ch0 + c4;
                glds16(alpha + g, &sIn[t][0][p * 256]);
                glds16(cwx   + g, &sIn[t][1][p * 256]);
            }
        // complete G_0; keep G_1..G_5 (40 ops) in flight
        asm volatile("s_waitcnt vmcnt(40)" ::: "memory");
    } else if (wid == 0) {
        if (lane < CPB) h = h0[ch0 + lane];
    } else {
        if (lane < CPB) hout[ch0 + lane] = h0[ch0 + lane];   // row 0
    }
    __builtin_amdgcn_s_barrier();
    __builtin_amdgcn_sched_barrier(0);

    // ---- main loop: one barrier per tile ----
    for (int tile = 0; tile < NT; ++tile) {
        if (wid == 0) {
            // COMPUTE tile from sIn[tile&7]; h trace -> sH[tile&1]
            const float* sA  = &sIn[tile & 7][0][0];
            const float* sW  = &sIn[tile & 7][1][0];
            float* sHc       = &sH[tile & 1][0];
            if (lane < CPB) {
                // (1) independent register burst (64 ds_read_b32)
                float aR[TT], wR[TT];   // wR = C2L*w (pre-scaled)
#pragma unroll
                for (int ts = 0; ts < TT; ++ts) {
                    aR[ts] = sA[ts * CPB + lane];
                    wR[ts] = sW[ts * CPB + lane];
                }
                __builtin_amdgcn_sched_barrier(0);   // pin burst above chain
                // (2) pure-VALU serial chain, 4 deep on zl
                float zl = fmaf(h, C2L, wR[0]);
#pragma unroll
                for (int ts = 0; ts < TT; ++ts) {
                    const float a    = aR[ts];
                    const float e    = __builtin_amdgcn_exp2f(zl);      // CHAIN
                    const float u    = 1.0f - a;                        // shadow
                    const float t2u  = u + u;                           // shadow
                    const float m    = fmaf(a, h, u);                   // shadow
                    const float ct2u = t2u * C2L;                       // shadow
                    const float r    = __builtin_amdgcn_rcpf(e + 1.0f); // CHAIN
                    if (ts < TT - 1) {
                        const float K = fmaf(m, C2L, wR[ts + 1]);       // shadow
                        zl = fmaf(-ct2u, r, K);                         // CHAIN
                    }
                    h = fmaf(-t2u, r, m);                               // off-chain
                    sHc[ts * SHS + lane] = h;
                }
            }
            asm volatile("s_waitcnt lgkmcnt(0)" ::: "memory");
            __builtin_amdgcn_sched_barrier(0);
        } else if (wid == 1) {
            // LOADER: stage tile+PF, then guarantee tile+1 is resident
            if (tile + PF < NT) {
                const int b  = (tile + PF) & 7;
                const int t0 = (tile + PF) * TT;
#pragma unroll
                for (int p = 0; p < TT / 8; ++p) {
                    const size_t g = (size_t)(t0 + p * 8 + q8) * NCH + ch0 + c4;
                    glds16(alpha + g, &sIn[b][0][p * 256]);
                    glds16(cwx   + g, &sIn[b][1][p * 256]);
                }
            }
            // counted drain: complete the burst for tile+1, keep the rest
            {
                const int rem = NT - 1 - tile;
                if (rem >= PF) {
                    asm volatile("s_waitcnt vmcnt(40)" ::: "memory");
                } else if (rem == 5) {
                    asm volatile("s_waitcnt vmcnt(32)" ::: "memory");
                } else if (rem == 4) {
                    asm volatile("s_waitcnt vmcnt(24)" ::: "memory");
                } else if (rem == 3) {
                    asm volatile("s_waitcnt vmcnt(16)" ::: "memory");
                } else if (rem == 2) {
                    asm volatile("s_waitcnt vmcnt(8)" ::: "memory");
                } else if (rem == 1) {
                    asm volatile("s_waitcnt vmcnt(0)" ::: "memory");
                }   // rem == 0: nothing outstanding
            }
            __builtin_amdgcn_sched_barrier(0);
        } else {
            // STORER: flush tile-1's h trace; fused out = h^2 * sigmoid(h)
            if (tile >= 1) {
                const float* sHs = &sH[(tile - 1) & 1][0];
                const int tb = (tile - 1) * TT;
#pragma unroll
                for (int i = 0; i < TT / 8; ++i) {
                    const int tsrow = i * 8 + q8;
                    const float4 hv = *reinterpret_cast<const float4*>(
                        &sHs[tsrow * SHS + c4]);
                    *reinterpret_cast<float4*>(
                        &hout[(size_t)(tb + tsrow + 1) * NCH + ch0 + c4]) = hv;
                    float4 o;
                    o.x = hv.x * hv.x * sigmoid_f(hv.x);
                    o.y = hv.y * hv.y * sigmoid_f(hv.y);
                    o.z = hv.z * hv.z * sigmoid_f(hv.z);
                    o.w = hv.w * hv.w * sigmoid_f(hv.w);
                    *reinterpret_cast<float4*>(
                        &out[(size_t)(tb + tsrow) * NCH + ch0 + c4]) = o;
                }
            }
        }
        __builtin_amdgcn_s_barrier();
        __builtin_amdgcn_sched_barrier(0);
    }

    // ---- epilogue: flush final tile ----
    if (wid == 2) {
        const float* sHs = &sH[(NT - 1) & 1][0];
        const int tb = (NT - 1) * TT;
#pragma unroll
        for (int i = 0; i < TT / 8; ++i) {
            const int tsrow = i * 8 + q8;
            const float4 hv = *reinterpret_cast<const float4*>(
                &sHs[tsrow * SHS + c4]);
            *reinterpret_cast<float4*>(
                &hout[(size_t)(tb + tsrow + 1) * NCH + ch0 + c4]) = hv;
            float4 o;
            o.x = hv.x * hv.x * sigmoid_f(hv.x);
            o.y = hv.y * hv.y * sigmoid_f(hv.y);
            o.z = hv.z * hv.z * sigmoid_f(hv.z);
            o.w = hv.w * hv.w * sigmoid_f(hv.w);
            *reinterpret_cast<float4*>(
                &out[(size_t)(tb + tsrow) * NCH + ch0 + c4]) = o;
        }
    }
}

// ---------------------------------------------------------------------------
extern "C" void kernel_launch(void* const* d_in, const int* in_sizes, int n_in,
                              void* d_out, int out_size, void* d_ws, size_t ws_size,
                              hipStream_t stream) {
    const float* x       = (const float*)d_in[0];  // [T,B,D]
    const float* h0      = (const float*)d_in[1];  // [B,D]
    const float* W_alpha = (const float*)d_in[2];  // [D,D]
    const float* b_alpha = (const float*)d_in[3];  // [D]
    const float* W_x     = (const float*)d_in[4];  // [D,D]
    const float* b       = (const float*)d_in[5];  // [D]

    float* out  = (float*)d_out;                              // [T,B,D]
    float* hout = out + (size_t)T_STEPS * BATCH * D_DIM;      // [T+1,B,D]

    // Workspace layout (~164 MB):
    //   alpha fp32 (64 MB) | cwx fp32 (64 MB) | x bf16 (32 MB) | Wc bf16 (4 MB)
    float* ws_alpha = (float*)d_ws;
    float* ws_wx    = ws_alpha + (size_t)M_ROWS * D_DIM;
    unsigned short* ws_x = (unsigned short*)(ws_wx + (size_t)M_ROWS * D_DIM);
    unsigned short* ws_W = ws_x + (size_t)M_ROWS * K_DIM;

    // 1) convert x, W_alpha, W_x to bf16
    {
        int n4 = M_ROWS * K_DIM / 4;
        cvt_bf16_kernel<<<(n4 + 255) / 256, 256, 0, stream>>>(x, ws_x, n4);
    }
    {
        int n4 = D_DIM * K_DIM / 4;
        cvt_bf16_kernel<<<(n4 + 255) / 256, 256, 0, stream>>>(W_alpha, ws_W, n4);
        cvt_bf16_kernel<<<(n4 + 255) / 256, 256, 0, stream>>>(
            W_x, ws_W + (size_t)D_DIM * K_DIM, n4);
    }

    // 2) fused GEMM (single-buffer BK=64) + bias/sigmoid/C2L epilogue
    {
        dim3 grid(N_COLS / BN, M_ROWS / BM);   // (16, 128)
        gemm_kernel<<<grid, 256, 0, stream>>>(ws_x, ws_W, b_alpha, b,
                                              ws_alpha, ws_wx);
    }

    // 3) sequential scan: 256 blocks x 3 waves (loader / compute / storer)
    scan_kernel<<<NCH / CPB, 192, 0, stream>>>(ws_alpha, ws_wx, h0, out, hout);
}

// Round 13
// 324.819 us; speedup vs baseline: 1.0443x; 1.0378x over previous
//
#include <hip/hip_runtime.h>
#include <hip/hip_bf16.h>
#include <cstdint>
#include <cstddef>

// Problem dims (fixed by the reference)
#define T_STEPS 2048
#define BATCH   8
#define D_DIM   1024
#define M_ROWS  (T_STEPS * BATCH)   // 16384 rows of x
#define N_COLS  (2 * D_DIM)         // 2048: W_alpha rows ++ W_x rows
#define K_DIM   D_DIM               // 1024
#define NCH     (BATCH * D_DIM)     // 8192 independent recurrence channels

// GEMM tiling: 128x128 tile, BK=64, SINGLE-buffer LDS (R12-validated 89.5us;
// dbuf/64KB variant cost +15us via occupancy 3->2 blocks/CU -- m132 lesson)
#define BM 128
#define BN 128
#define BK 64

typedef __bf16 bf16x8 __attribute__((ext_vector_type(8)));
typedef float  f32x4  __attribute__((ext_vector_type(4)));

#define C2L_CONST 2.88539008177792681472f   // 2*log2(e)

__device__ __forceinline__ unsigned short f2bf_rne(float f) {
    union { float f; unsigned u; } c; c.f = f;
    unsigned u = c.u;
    u += 0x7fffu + ((u >> 16) & 1u);   // round-to-nearest-even (inputs finite)
    return (unsigned short)(u >> 16);
}

__device__ __forceinline__ float sigmoid_f(float z) {
    return 1.0f / (1.0f + __expf(-z));
}

// async global -> LDS DMA, 16 B per lane; LDS dest = wave-uniform base + lane*16
__device__ __forceinline__ void glds16(const void* gptr, void* lptr) {
    __builtin_amdgcn_global_load_lds(
        (const __attribute__((address_space(1))) unsigned int*)gptr,
        (__attribute__((address_space(3))) unsigned int*)lptr,
        16, 0, 0);
}

// ---------------------------------------------------------------------------
// Fused fp32 -> bf16 convert for all three inputs in ONE launch (R13: saves
// two launch gaps). Region 0: x (n4x float4s); 1: W_alpha; 2: W_x.
// ---------------------------------------------------------------------------
__global__ __launch_bounds__(256)
void cvt_all_kernel(const float* __restrict__ x,
                    const float* __restrict__ Wa,
                    const float* __restrict__ Wx,
                    unsigned short* __restrict__ dx,    // ws_x
                    unsigned short* __restrict__ dW)    // ws_W (Wa ++ Wx)
{
    const int n4x = M_ROWS * K_DIM / 4;          // 4,194,304
    const int n4w = D_DIM * K_DIM / 4;           //   262,144
    const int total = n4x + 2 * n4w;
    const int stride = gridDim.x * blockDim.x;
    for (int i = blockIdx.x * blockDim.x + threadIdx.x; i < total; i += stride) {
        const float* src;
        unsigned short* dst;
        int j;
        if (i < n4x)               { src = x;  dst = dx;            j = i; }
        else if (i < n4x + n4w)    { src = Wa; dst = dW;            j = i - n4x; }
        else                       { src = Wx; dst = dW + (size_t)D_DIM * K_DIM;
                                     j = i - n4x - n4w; }
        float4 v = reinterpret_cast<const float4*>(src)[j];
        ushort4 o;
        o.x = f2bf_rne(v.x); o.y = f2bf_rne(v.y);
        o.z = f2bf_rne(v.z); o.w = f2bf_rne(v.w);
        reinterpret_cast<ushort4*>(dst)[j] = o;
    }
}

// ---------------------------------------------------------------------------
// Fused bf16 MFMA GEMM, BK=64 + block-XOR LDS swizzle, single-buffer
// (exact R12-validated structure, 89.5us / 768 TF).
//   out[m,n] = sum_k x[m,k] * Wc[n,k]
//   n <  1024 -> alpha_out = sigmoid(acc + b_alpha[n])
//   n >= 1024 -> wx_out    = C2L * (acc + b[n-1024])   [pre-scaled for scan]
// ---------------------------------------------------------------------------
__global__ __launch_bounds__(256, 2)
void gemm_kernel(const unsigned short* __restrict__ A,   // [M][K] bf16 (x)
                 const unsigned short* __restrict__ Bm,  // [N][K] bf16 (W_alpha ++ W_x)
                 const float* __restrict__ b_alpha,      // [D]
                 const float* __restrict__ b_x,          // [D]
                 float* __restrict__ alpha_out,          // [M][D] fp32
                 float* __restrict__ wx_out)             // [M][D] fp32 (C2L-scaled)
{
    __shared__ unsigned short sA[BM * BK];   // 16 KB
    __shared__ unsigned short sB[BN * BK];   // 16 KB

    const int tid  = threadIdx.x;
    const int wave = tid >> 6;
    const int lane = tid & 63;

    // XCD swizzle: grid is (16, 128) = 2048 wgs; 2048 % 8 == 0 -> bijective
    const int orig = blockIdx.y * 16 + blockIdx.x;
    const int swz  = (orig & 7) * 256 + (orig >> 3);
    const int rowBase = (swz >> 4) * BM;
    const int colBase = (swz & 15) * BN;

    const int wr = (wave >> 1) * 64;
    const int wc = (wave & 1) * 64;

    const int laneHi = lane >> 4;           // 0..3
    const int laneLo = lane & 15;
    const int rxor   = laneLo & 7;          // row&7 for fragment reads

    // DMA staging: 8 rows per glds16; source col block XOR-swizzled
    const int dRow   = lane >> 3;                    // 0..7
    const int dColSw = ((lane & 7) ^ dRow) * 8;      // shorts

    f32x4 acc[4][4];
#pragma unroll
    for (int i = 0; i < 4; i++)
#pragma unroll
        for (int j = 0; j < 4; j++)
            acc[i][j] = (f32x4)(0.0f);

    for (int k0 = 0; k0 < K_DIM; k0 += BK) {
#pragma unroll
        for (int p = 0; p < 4; ++p) {
            const int seg = wave * 4 + p;   // 8-row segment index, 0..15
            glds16(A + (size_t)(rowBase + seg * 8 + dRow) * K_DIM + k0 + dColSw,
                   &sA[seg * 512]);
            glds16(Bm + (size_t)(colBase + seg * 8 + dRow) * K_DIM + k0 + dColSw,
                   &sB[seg * 512]);
        }
        __syncthreads();   // drains vmcnt(0) -> LDS tiles ready

#pragma unroll
        for (int kk = 0; kk < 2; ++kk) {
            bf16x8 af[4], bfr[4];
#pragma unroll
            for (int i = 0; i < 4; i++) {
                const int row = wr + i * 16 + laneLo;
                af[i] = *reinterpret_cast<const bf16x8*>(
                    &sA[row * BK + (((kk << 2) + laneHi) ^ rxor) * 8]);
            }
#pragma unroll
            for (int j = 0; j < 4; j++) {
                const int row = wc + j * 16 + laneLo;
                bfr[j] = *reinterpret_cast<const bf16x8*>(
                    &sB[row * BK + (((kk << 2) + laneHi) ^ rxor) * 8]);
            }
#pragma unroll
            for (int i = 0; i < 4; i++)
#pragma unroll
                for (int j = 0; j < 4; j++)
                    acc[i][j] = __builtin_amdgcn_mfma_f32_16x16x32_bf16(
                        af[i], bfr[j], acc[i][j], 0, 0, 0);
        }
        __syncthreads();   // all reads done; LDS free for next k-step
    }

    // Epilogue. C/D layout: col = lane&15, row = (lane>>4)*4 + reg  [m89/m91]
#pragma unroll
    for (int i = 0; i < 4; i++) {
        int row = rowBase + wr + i * 16 + laneHi * 4;
#pragma unroll
        for (int j = 0; j < 4; j++) {
            int col = colBase + wc + j * 16 + laneLo;
            if (col < D_DIM) {
                float bias = b_alpha[col];
#pragma unroll
                for (int r = 0; r < 4; r++) {
                    float z = acc[i][j][r] + bias;
                    alpha_out[(size_t)(row + r) * D_DIM + col] = sigmoid_f(z);
                }
            } else {
                int c2 = col - D_DIM;
                float bias = b_x[c2];
#pragma unroll
                for (int r = 0; r < 4; r++)
                    wx_out[(size_t)(row + r) * D_DIM + c2] =
                        (acc[i][j][r] + bias) * C2L_CONST;   // pre-scaled
            }
        }
    }
}

// ---------------------------------------------------------------------------
// Sequential scan v11 == v9 EXACT REVERT (R11-validated ~65us).
//   R12 lesson: the lone in-order compute wave is ISSUE-bound; the K-route's
//   "+2 shadow VALU for a shorter chain" trade regressed 13us because there
//   are no free shadow slots. v9's 6-VALU body is the measured optimum:
//     exp2, e+1, rcp, u=1-a, t2u=u+u, m=fma(a,h,u),
//     h=fma(-t2u,r,m), zl=fma(h,C2L,cw')   = 2 trans + 6 VALU + 1 ds_write.
//   Register burst (R9) keeps LDS latency off the chain; loader/storer/
//   barriers/counted-vmcnt identical to v7/v8/v9 (validated).
// ---------------------------------------------------------------------------
#define TT   32
#define NT   (T_STEPS / TT)   // 64 tiles
#define PF   6                // prefetch distance (tiles)
#define CPB  32               // channels per block
#define SHS  36               // sH row stride (floats), padded

__global__ __launch_bounds__(192)
void scan_kernel(const float* __restrict__ alpha,  // [T][NCH]
                 const float* __restrict__ cwx,    // [T][NCH]  (= C2L*(Wx+b))
                 const float* __restrict__ h0,     // [NCH]
                 float* __restrict__ out,          // [T][NCH]
                 float* __restrict__ hout)         // [T+1][NCH]
{
    __shared__ float sIn[8][2][TT * CPB];   // [buf][0=alpha,1=cwx]  64 KB
    __shared__ float sH[2][TT * SHS];       // h ring, padded        9 KB

    const int lane = threadIdx.x & 63;
    const int wid  = threadIdx.x >> 6;
    const int ch0  = blockIdx.x * CPB;

    const float C2L = C2L_CONST;

    // loader/storer lane mapping (16 B per lane): 8 lanes per timestep
    const int q8 = lane >> 3;            // timestep sub-offset 0..7
    const int c4 = (lane & 7) * 4;       // channel group

    float h = 0.0f;

    // ---- prologue ----
    if (wid == 1) {
        // stage tiles 0..PF-1 (6 bursts x 8 ops = 48 outstanding)
#pragma unroll
        for (int t = 0; t < PF; ++t)
#pragma unroll
            for (int p = 0; p < TT / 8; ++p) {
                const size_t g = (size_t)(t * TT + p * 8 + q8) * NCH + ch0 + c4;
                glds16(alpha + g, &sIn[t][0][p * 256]);
                glds16(cwx   + g, &sIn[t][1][p * 256]);
            }
        // complete G_0; keep G_1..G_5 (40 ops) in flight
        asm volatile("s_waitcnt vmcnt(40)" ::: "memory");
    } else if (wid == 0) {
        if (lane < CPB) h = h0[ch0 + lane];
    } else {
        if (lane < CPB) hout[ch0 + lane] = h0[ch0 + lane];   // row 0
    }
    __builtin_amdgcn_s_barrier();
    __builtin_amdgcn_sched_barrier(0);

    // ---- main loop: one barrier per tile ----
    for (int tile = 0; tile < NT; ++tile) {
        if (wid == 0) {
            // COMPUTE tile from sIn[tile&7]; h trace -> sH[tile&1]
            const float* sA  = &sIn[tile & 7][0][0];
            const float* sW  = &sIn[tile & 7][1][0];
            float* sHc       = &sH[tile & 1][0];
            if (lane < CPB) {
                // (1) independent register burst (64 ds_read_b32)
                float aR[TT], wR[TT];   // wR = C2L*w (pre-scaled)
#pragma unroll
                for (int ts = 0; ts < TT; ++ts) {
                    aR[ts] = sA[ts * CPB + lane];
                    wR[ts] = sW[ts * CPB + lane];
                }
                __builtin_amdgcn_sched_barrier(0);   // pin burst above chain
                // (2) pure-VALU serial chain (v9 body)
                float zl = fmaf(h, C2L, wR[0]);
#pragma unroll
                for (int ts = 0; ts < TT; ++ts) {
                    const float a   = aR[ts];
                    const float e   = __builtin_amdgcn_exp2f(zl);      // CHAIN
                    const float u   = 1.0f - a;                        // shadow
                    const float t2u = u + u;                           // shadow
                    const float m   = fmaf(a, h, u);                   // shadow
                    const float r   = __builtin_amdgcn_rcpf(e + 1.0f); // CHAIN
                    h = fmaf(-t2u, r, m);                              // CHAIN
                    if (ts < TT - 1) zl = fmaf(h, C2L, wR[ts + 1]);    // CHAIN
                    sHc[ts * SHS + lane] = h;
                }
            }
            asm volatile("s_waitcnt lgkmcnt(0)" ::: "memory");
            __builtin_amdgcn_sched_barrier(0);
        } else if (wid == 1) {
            // LOADER: stage tile+PF, then guarantee tile+1 is resident
            if (tile + PF < NT) {
                const int b  = (tile + PF) & 7;
                const int t0 = (tile + PF) * TT;
#pragma unroll
                for (int p = 0; p < TT / 8; ++p) {
                    const size_t g = (size_t)(t0 + p * 8 + q8) * NCH + ch0 + c4;
                    glds16(alpha + g, &sIn[b][0][p * 256]);
                    glds16(cwx   + g, &sIn[b][1][p * 256]);
                }
            }
            // counted drain: complete the burst for tile+1, keep the rest
            {
                const int rem = NT - 1 - tile;
                if (rem >= PF) {
                    asm volatile("s_waitcnt vmcnt(40)" ::: "memory");
                } else if (rem == 5) {
                    asm volatile("s_waitcnt vmcnt(32)" ::: "memory");
                } else if (rem == 4) {
                    asm volatile("s_waitcnt vmcnt(24)" ::: "memory");
                } else if (rem == 3) {
                    asm volatile("s_waitcnt vmcnt(16)" ::: "memory");
                } else if (rem == 2) {
                    asm volatile("s_waitcnt vmcnt(8)" ::: "memory");
                } else if (rem == 1) {
                    asm volatile("s_waitcnt vmcnt(0)" ::: "memory");
                }   // rem == 0: nothing outstanding
            }
            __builtin_amdgcn_sched_barrier(0);
        } else {
            // STORER: flush tile-1's h trace; fused out = h^2 * sigmoid(h)
            if (tile >= 1) {
                const float* sHs = &sH[(tile - 1) & 1][0];
                const int tb = (tile - 1) * TT;
#pragma unroll
                for (int i = 0; i < TT / 8; ++i) {
                    const int tsrow = i * 8 + q8;
                    const float4 hv = *reinterpret_cast<const float4*>(
                        &sHs[tsrow * SHS + c4]);
                    *reinterpret_cast<float4*>(
                        &hout[(size_t)(tb + tsrow + 1) * NCH + ch0 + c4]) = hv;
                    float4 o;
                    o.x = hv.x * hv.x * sigmoid_f(hv.x);
                    o.y = hv.y * hv.y * sigmoid_f(hv.y);
                    o.z = hv.z * hv.z * sigmoid_f(hv.z);
                    o.w = hv.w * hv.w * sigmoid_f(hv.w);
                    *reinterpret_cast<float4*>(
                        &out[(size_t)(tb + tsrow) * NCH + ch0 + c4]) = o;
                }
            }
        }
        __builtin_amdgcn_s_barrier();
        __builtin_amdgcn_sched_barrier(0);
    }

    // ---- epilogue: flush final tile ----
    if (wid == 2) {
        const float* sHs = &sH[(NT - 1) & 1][0];
        const int tb = (NT - 1) * TT;
#pragma unroll
        for (int i = 0; i < TT / 8; ++i) {
            const int tsrow = i * 8 + q8;
            const float4 hv = *reinterpret_cast<const float4*>(
                &sHs[tsrow * SHS + c4]);
            *reinterpret_cast<float4*>(
                &hout[(size_t)(tb + tsrow + 1) * NCH + ch0 + c4]) = hv;
            float4 o;
            o.x = hv.x * hv.x * sigmoid_f(hv.x);
            o.y = hv.y * hv.y * sigmoid_f(hv.y);
            o.z = hv.z * hv.z * sigmoid_f(hv.z);
            o.w = hv.w * hv.w * sigmoid_f(hv.w);
            *reinterpret_cast<float4*>(
                &out[(size_t)(tb + tsrow) * NCH + ch0 + c4]) = o;
        }
    }
}

// ---------------------------------------------------------------------------
extern "C" void kernel_launch(void* const* d_in, const int* in_sizes, int n_in,
                              void* d_out, int out_size, void* d_ws, size_t ws_size,
                              hipStream_t stream) {
    const float* x       = (const float*)d_in[0];  // [T,B,D]
    const float* h0      = (const float*)d_in[1];  // [B,D]
    const float* W_alpha = (const float*)d_in[2];  // [D,D]
    const float* b_alpha = (const float*)d_in[3];  // [D]
    const float* W_x     = (const float*)d_in[4];  // [D,D]
    const float* b       = (const float*)d_in[5];  // [D]

    float* out  = (float*)d_out;                              // [T,B,D]
    float* hout = out + (size_t)T_STEPS * BATCH * D_DIM;      // [T+1,B,D]

    // Workspace layout (~164 MB):
    //   alpha fp32 (64 MB) | cwx fp32 (64 MB) | x bf16 (32 MB) | Wc bf16 (4 MB)
    float* ws_alpha = (float*)d_ws;
    float* ws_wx    = ws_alpha + (size_t)M_ROWS * D_DIM;
    unsigned short* ws_x = (unsigned short*)(ws_wx + (size_t)M_ROWS * D_DIM);
    unsigned short* ws_W = ws_x + (size_t)M_ROWS * K_DIM;

    // 1) convert x, W_alpha, W_x to bf16 -- ONE fused launch
    cvt_all_kernel<<<2048, 256, 0, stream>>>(x, W_alpha, W_x, ws_x, ws_W);

    // 2) fused GEMM (single-buffer BK=64) + bias/sigmoid/C2L epilogue
    {
        dim3 grid(N_COLS / BN, M_ROWS / BM);   // (16, 128)
        gemm_kernel<<<grid, 256, 0, stream>>>(ws_x, ws_W, b_alpha, b,
                                              ws_alpha, ws_wx);
    }

    // 3) sequential scan: 256 blocks x 3 waves (loader / compute / storer)
    scan_kernel<<<NCH / CPB, 192, 0, stream>>>(ws_alpha, ws_wx, h0, out, hout);
}